// Round 2
// baseline (279.228 us; speedup 1.0000x reference)
//
#include <hip/hip_runtime.h>
#include <stdint.h>

#define HID 2048
#define DHEAD 128
#define SEQL 2048
#define QKSCALE 0.08838834764831845f  // 1/sqrt(128)

typedef __attribute__((ext_vector_type(4))) float f32x4;
typedef __attribute__((ext_vector_type(8))) short s16x8;

__device__ __forceinline__ unsigned short bf16_rne(float f) {
  union { float f; unsigned u; } v; v.f = f;
  return (unsigned short)((v.u + 0x7FFFu + ((v.u >> 16) & 1u)) >> 16);
}

__device__ __forceinline__ void gload_lds16(const void* g, void* l) {
  __builtin_amdgcn_global_load_lds(
      (__attribute__((address_space(1))) unsigned int*)(void*)g,
      (__attribute__((address_space(3))) unsigned int*)l, 16, 0, 0);
}

// ---------- f32 -> bf16 conversion, 8 elems/thread ----------
__global__ __launch_bounds__(256) void cvt_bf16_k(const float* __restrict__ in,
                                                  unsigned short* __restrict__ out,
                                                  int n8) {
  int i = blockIdx.x * 256 + threadIdx.x;
  if (i >= n8) return;
  const f32x4* p = (const f32x4*)in;
  f32x4 a = p[2 * i], b = p[2 * i + 1];
  union { s16x8 v; unsigned short s[8]; } o;
  o.s[0] = bf16_rne(a[0]); o.s[1] = bf16_rne(a[1]);
  o.s[2] = bf16_rne(a[2]); o.s[3] = bf16_rne(a[3]);
  o.s[4] = bf16_rne(b[0]); o.s[5] = bf16_rne(b[1]);
  o.s[6] = bf16_rne(b[2]); o.s[7] = bf16_rne(b[3]);
  ((s16x8*)out)[i] = o.v;
}

// ---------- tile staging: global -> LDS, 16B/lane, XOR-swizzled source ----------
// Tile is (1024 >> LOG2SLOTS) rows x ((1<<LOG2SLOTS)*8) bf16 cols; LDS dest linear.
template <int LOG2SLOTS>
__device__ __forceinline__ void stage_tile(const unsigned short* __restrict__ src,
                                           int ld, char* smem, int t) {
  int w = t >> 6;
#pragma unroll
  for (int i = 0; i < 4; ++i) {
    int c = i * 256 + t;
    int row = c >> LOG2SLOTS;
    int slot = c & ((1 << LOG2SLOTS) - 1);
    gload_lds16(src + row * ld + ((slot ^ (row & 7)) << 3),
                smem + (i * 256 + w * 64) * 16);
  }
}

// ---------- C = A[M,K] @ Bw[N,K]^T, bf16 in, fp32 accum ----------
// MODE 0: bf16 C row-major. MODE 1: f32 C row-major.
// MODE 2: KV split: cols 0..127 -> Kbuf[M][128] bf16; cols 128..255 -> Vt[b][d][s] bf16.
template <int MODE>
__global__ __launch_bounds__(256, 2) void gemm_bt(
    const unsigned short* __restrict__ A, const unsigned short* __restrict__ Bw,
    void* __restrict__ Cout, int M, int N, int K, unsigned short* __restrict__ Vt) {
  __shared__ char As[128 * 64 * 2];
  __shared__ char Bs[128 * 64 * 2];
  int t = threadIdx.x;
  int lane = t & 63, w = t >> 6;
  int wm = w >> 1, wn = w & 1;
  int l15 = lane & 15, l4 = lane >> 4;
  int tm = blockIdx.y * 128, tn = blockIdx.x * 128;

  f32x4 acc[4][4] = {};

  for (int kt = 0; kt < K; kt += 64) {
    stage_tile<3>(A + tm * K + kt, K, As, t);
    stage_tile<3>(Bw + tn * K + kt, K, Bs, t);
    __syncthreads();
    s16x8 af[4][2], bfr[4][2];
#pragma unroll
    for (int m = 0; m < 4; ++m)
#pragma unroll
      for (int kk = 0; kk < 2; ++kk) {
        int row = wm * 64 + m * 16 + l15;
        af[m][kk] = *(const s16x8*)(As + row * 128 + (((kk * 4 + l4) ^ (row & 7)) << 4));
      }
#pragma unroll
    for (int n = 0; n < 4; ++n)
#pragma unroll
      for (int kk = 0; kk < 2; ++kk) {
        int row = wn * 64 + n * 16 + l15;
        bfr[n][kk] = *(const s16x8*)(Bs + row * 128 + (((kk * 4 + l4) ^ (row & 7)) << 4));
      }
#pragma unroll
    for (int m = 0; m < 4; ++m)
#pragma unroll
      for (int n = 0; n < 4; ++n)
#pragma unroll
        for (int kk = 0; kk < 2; ++kk)
          acc[m][n] = __builtin_amdgcn_mfma_f32_16x16x32_bf16(af[m][kk], bfr[n][kk],
                                                              acc[m][n], 0, 0, 0);
    __syncthreads();
  }

#pragma unroll
  for (int m = 0; m < 4; ++m)
#pragma unroll
    for (int n = 0; n < 4; ++n) {
      int col = tn + wn * 64 + n * 16 + l15;
#pragma unroll
      for (int j = 0; j < 4; ++j) {
        int row = tm + wm * 64 + m * 16 + l4 * 4 + j;
        float v = acc[m][n][j];
        if (MODE == 0) {
          ((unsigned short*)Cout)[row * N + col] = bf16_rne(v);
        } else if (MODE == 1) {
          ((float*)Cout)[row * N + col] = v;
        } else {
          if (col < 128) {
            ((unsigned short*)Cout)[row * 128 + col] = bf16_rne(v);
          } else {
            int d = col - 128, bb = row >> 11, s = row & 2047;
            Vt[((bb * 128 + d) << 11) + s] = bf16_rne(v);
          }
        }
      }
    }
}

// ---------- flash attention: Q[4096,2048] x Kbuf[4096,128] x Vt[2,128,2048] -> AO ----------
__global__ __launch_bounds__(256, 2) void attn_k(
    const unsigned short* __restrict__ Q, const unsigned short* __restrict__ Kb,
    const unsigned short* __restrict__ Vt, unsigned short* __restrict__ AO) {
  __shared__ char Ks[64 * 256];   // 64 keys x 128 bf16 (swizzled)
  __shared__ char Vs[128 * 128];  // 128 d   x 64 keys  (swizzled)
  __shared__ char Ps[4 * 4096];   // per-wave P tile 32x64 bf16 (swizzled)
  int t = threadIdx.x;
  int lane = t & 63, w = t >> 6;
  int l15 = lane & 15, l4 = lane >> 4;
  int qt = blockIdx.x, bh = blockIdx.y;
  int b = bh >> 4, h = bh & 15;
  int qg = b * SEQL + qt * 128 + w * 32;  // this wave's first global q row
  char* Psw = Ps + w * 4096;

  // Q fragments hoisted to registers (one-time strided load)
  s16x8 qf[2][4];
#pragma unroll
  for (int m = 0; m < 2; ++m)
#pragma unroll
    for (int kc = 0; kc < 4; ++kc)
      qf[m][kc] = *(const s16x8*)(Q + (qg + m * 16 + l15) * HID + h * DHEAD + kc * 32 + l4 * 8);

  f32x4 oacc[2][8] = {};
  float rm[2][4], rl[2][4];
#pragma unroll
  for (int m = 0; m < 2; ++m)
#pragma unroll
    for (int j = 0; j < 4; ++j) { rm[m][j] = -1e30f; rl[m][j] = 0.f; }

  for (int kv = 0; kv < SEQL; kv += 64) {
    // stage K tile: 64 rows x 256B (16 slots/row)
#pragma unroll
    for (int i = 0; i < 4; ++i) {
      int c = i * 256 + t;
      int row = c >> 4, slot = c & 15;
      gload_lds16(Kb + (b * SEQL + kv + row) * DHEAD + ((slot ^ (row & 7)) << 3),
                  Ks + (i * 256 + w * 64) * 16);
    }
    // stage Vt tile: 128 rows x 128B (8 slots/row)
#pragma unroll
    for (int i = 0; i < 4; ++i) {
      int c = i * 256 + t;
      int row = c >> 3, slot = c & 7;
      gload_lds16(Vt + (b * DHEAD + row) * SEQL + kv + ((slot ^ (row & 7)) << 3),
                  Vs + (i * 256 + w * 64) * 16);
    }
    __syncthreads();

    // S = Q K^T (raw, scale applied in softmax)
    f32x4 sacc[2][4] = {};
#pragma unroll
    for (int n = 0; n < 4; ++n) {
      int krow = n * 16 + l15;
#pragma unroll
      for (int kc = 0; kc < 4; ++kc) {
        s16x8 kf = *(const s16x8*)(Ks + krow * 256 + (((kc * 4 + l4) ^ (krow & 7)) << 4));
        sacc[0][n] = __builtin_amdgcn_mfma_f32_16x16x32_bf16(qf[0][kc], kf, sacc[0][n], 0, 0, 0);
        sacc[1][n] = __builtin_amdgcn_mfma_f32_16x16x32_bf16(qf[1][kc], kf, sacc[1][n], 0, 0, 0);
      }
    }

    // online softmax (wave-parallel; rows live in 16-lane groups)
#pragma unroll
    for (int m = 0; m < 2; ++m) {
      float tmax[4], mnew[4], corr[4], rsum[4];
#pragma unroll
      for (int j = 0; j < 4; ++j) {
        tmax[j] = fmaxf(fmaxf(sacc[m][0][j], sacc[m][1][j]),
                        fmaxf(sacc[m][2][j], sacc[m][3][j]));
#pragma unroll
        for (int msk = 1; msk < 16; msk <<= 1)
          tmax[j] = fmaxf(tmax[j], __shfl_xor(tmax[j], msk));
        mnew[j] = fmaxf(rm[m][j], tmax[j] * QKSCALE);
        corr[j] = __expf(rm[m][j] - mnew[j]);
        rm[m][j] = mnew[j];
        rsum[j] = 0.f;
      }
#pragma unroll
      for (int n = 0; n < 4; ++n) {
        int pcol = n * 16 + l15;
#pragma unroll
        for (int j = 0; j < 4; ++j) {
          float p = __expf(sacc[m][n][j] * QKSCALE - mnew[j]);
          rsum[j] += p;
          int prow = m * 16 + l4 * 4 + j;
          *(unsigned short*)(Psw + prow * 128 + (((pcol >> 3) ^ (prow & 7)) << 4) +
                             (pcol & 7) * 2) = bf16_rne(p);
        }
      }
#pragma unroll
      for (int j = 0; j < 4; ++j) {
#pragma unroll
        for (int msk = 1; msk < 16; msk <<= 1)
          rsum[j] += __shfl_xor(rsum[j], msk);
        rl[m][j] = rl[m][j] * corr[j] + rsum[j];
      }
#pragma unroll
      for (int n = 0; n < 8; ++n)
#pragma unroll
        for (int j = 0; j < 4; ++j) oacc[m][n][j] *= corr[j];
    }

    __syncthreads();  // order P writes before PV reads (also defends vs TBAA reorder)

    // O += P V
#pragma unroll
    for (int kc2 = 0; kc2 < 2; ++kc2) {
      s16x8 pa[2];
#pragma unroll
      for (int m = 0; m < 2; ++m) {
        int row = m * 16 + l15;
        pa[m] = *(const s16x8*)(Psw + row * 128 + (((kc2 * 4 + l4) ^ (row & 7)) << 4));
      }
#pragma unroll
      for (int n = 0; n < 8; ++n) {
        int vrow = n * 16 + l15;
        s16x8 vf = *(const s16x8*)(Vs + vrow * 128 + (((kc2 * 4 + l4) ^ (vrow & 7)) << 4));
        oacc[0][n] = __builtin_amdgcn_mfma_f32_16x16x32_bf16(pa[0], vf, oacc[0][n], 0, 0, 0);
        oacc[1][n] = __builtin_amdgcn_mfma_f32_16x16x32_bf16(pa[1], vf, oacc[1][n], 0, 0, 0);
      }
    }
    __syncthreads();
  }

  // epilogue: O / l -> bf16 AO[row][h*128+d]
#pragma unroll
  for (int m = 0; m < 2; ++m) {
    float inv[4];
#pragma unroll
    for (int j = 0; j < 4; ++j) inv[j] = 1.f / rl[m][j];
#pragma unroll
    for (int n = 0; n < 8; ++n) {
      int col = h * DHEAD + n * 16 + l15;
#pragma unroll
      for (int j = 0; j < 4; ++j) {
        int row = qg + m * 16 + l4 * 4 + j;
        AO[row * HID + col] = bf16_rne(oacc[m][n][j] * inv[j]);
      }
    }
  }
}

extern "C" void kernel_launch(void* const* d_in, const int* in_sizes, int n_in,
                              void* d_out, int out_size, void* d_ws, size_t ws_size,
                              hipStream_t stream) {
  const float* x  = (const float*)d_in[0];
  const float* qw = (const float*)d_in[1];
  const float* kw = (const float*)d_in[2];
  const float* vw = (const float*)d_in[3];
  const float* ow = (const float*)d_in[4];

  char* ws = (char*)d_ws;
  // workspace layout (bytes); AO aliases xb (xb dead after KV GEMM), owb aliases qwb
  unsigned short* xb   = (unsigned short*)(ws);                 // 16 MB [4096,2048]
  unsigned short* qwb  = (unsigned short*)(ws + 16777216);      // 8 MB  [2048,2048]
  unsigned short* owb  = qwb;                                   // reused after Q GEMM
  unsigned short* kvwb = (unsigned short*)(ws + 25165824);      // 1 MB  [256,2048]
  unsigned short* Qb   = (unsigned short*)(ws + 26214400);      // 16 MB [4096,2048]
  unsigned short* Kbuf = (unsigned short*)(ws + 42991616);      // 1 MB  [4096,128]
  unsigned short* Vtb  = (unsigned short*)(ws + 44040192);      // 1 MB  [2,128,2048]
  unsigned short* AOb  = xb;                                    // reused after KV GEMM

  // f32 -> bf16 conversions
  cvt_bf16_k<<<4096, 256, 0, stream>>>(x,  xb,   1048576);
  cvt_bf16_k<<<2048, 256, 0, stream>>>(qw, qwb,  524288);
  cvt_bf16_k<<<128,  256, 0, stream>>>(kw, kvwb, 32768);
  cvt_bf16_k<<<128,  256, 0, stream>>>(vw, kvwb + 262144, 32768);

  // Q projection: [4096,2048] = xb @ qwb^T
  gemm_bt<0><<<dim3(16, 32), 256, 0, stream>>>(xb, qwb, Qb, 4096, 2048, 2048, nullptr);
  // o_w conversion (after Q GEMM: owb aliases qwb)
  cvt_bf16_k<<<2048, 256, 0, stream>>>(ow, owb, 524288);
  // KV projection: K rows + V transposed scatter
  gemm_bt<2><<<dim3(2, 32), 256, 0, stream>>>(xb, kvwb, Kbuf, 4096, 256, 2048, Vtb);
  // attention
  attn_k<<<dim3(16, 32), 256, 0, stream>>>(Qb, Kbuf, Vtb, AOb);
  // output projection -> f32
  gemm_bt<1><<<dim3(16, 32), 256, 0, stream>>>(AOb, owb, d_out, 4096, 2048, 2048, nullptr);
}